// Round 5
// baseline (193.629 us; speedup 1.0000x reference)
//
#include <hip/hip_runtime.h>
#include <stdint.h>

#pragma clang fp contract(off)

#define B_ 2
#define P_ 512
#define C_ 21
#define CF 20            // foreground classes
#define DET 100
#define SCORE_THRESH 0.05f
#define NMS_THR 0.5f
#define BBOX_CLIP 4.135166556742356f   // log(1000/16)
#define NC (CF * DET)    // 2000 candidates per image
#define CHUNK 2048

typedef unsigned long long u64;
typedef unsigned int u32;

__device__ __forceinline__ u32 f2o(float f) {
  u32 u = __float_as_uint(f);
  return (u & 0x80000000u) ? ~u : (u | 0x80000000u);
}
__device__ __forceinline__ float o2f(u32 o) {
  u32 u = (o & 0x80000000u) ? (o ^ 0x80000000u) : ~o;
  return __uint_as_float(u);
}

// ---------------------------------------------------------------------------
// exact convex quad-quad intersection area — register-resident, bit-identical
// float op order vs reference (fp contract off). Clips quad q by edges of r.
// ---------------------------------------------------------------------------
__device__ __forceinline__ float inter_area_reg(const float qx[4], const float qy[4],
                                                const float rx[4], const float ry[4]) {
  float px_[8], py_[8];
  #pragma unroll
  for (int t = 0; t < 8; ++t) { px_[t] = (t < 4) ? qx[t] : 0.f; py_[t] = (t < 4) ? qy[t] : 0.f; }
  int n = 4;
  #pragma unroll
  for (int e = 0; e < 4; ++e) {
    float a0 = rx[e], a1 = ry[e];
    float b0 = rx[(e + 1) & 3], b1 = ry[(e + 1) & 3];
    float dx = b0 - a0, dy = b1 - a1;
    float ox_[8], oy_[8];
    #pragma unroll
    for (int t = 0; t < 8; ++t) { ox_[t] = 0.f; oy_[t] = 0.f; }
    float cr[8];
    #pragma unroll
    for (int t = 0; t < 8; ++t) cr[t] = dx * (py_[t] - a1) - dy * (px_[t] - a0);
    int m = 0;
    int nn = (n > 1) ? n : 1;
    #pragma unroll
    for (int t = 0; t < 8; ++t) {
      bool act = t < n;
      float sx = px_[t], sy = py_[t];
      float ex, ey, ce;
      if (t == 7) { ex = px_[0]; ey = py_[0]; ce = cr[0]; }
      else {
        bool wrap = (t + 1 == nn);
        ex = wrap ? px_[0] : px_[t + 1];
        ey = wrap ? py_[0] : py_[t + 1];
        ce = wrap ? cr[0] : cr[t + 1];
      }
      float cs = cr[t];
      float denom = cs - ce;
      float dn = (fabsf(denom) > 1e-12f) ? denom : 1e-12f;
      float tt = cs / dn;
      float ipx = sx + tt * (ex - sx);
      float ipy = sy + tt * (ey - sy);
      bool s_in = cs >= 0.f, e_in = ce >= 0.f;
      bool app1 = act && (s_in != e_in);
      #pragma unroll
      for (int s2 = 0; s2 < 8; ++s2) {
        bool wr = app1 && (m == s2);
        ox_[s2] = wr ? ipx : ox_[s2];
        oy_[s2] = wr ? ipy : oy_[s2];
      }
      m += app1 ? 1 : 0;
      bool app2 = act && e_in;
      #pragma unroll
      for (int s2 = 0; s2 < 8; ++s2) {
        bool wr = app2 && (m == s2);
        ox_[s2] = wr ? ex : ox_[s2];
        oy_[s2] = wr ? ey : oy_[s2];
      }
      m += app2 ? 1 : 0;
    }
    n = m;
    #pragma unroll
    for (int t = 0; t < 8; ++t) { px_[t] = ox_[t]; py_[t] = oy_[t]; }
  }
  int nn = (n > 1) ? n : 1;
  float s = 0.f;
  #pragma unroll
  for (int t = 0; t < 8; ++t) {
    if (t < n) {
      float nx_x, nx_y;
      if (t == 7) { nx_x = px_[0]; nx_y = py_[0]; }
      else {
        bool wrap = (t + 1 == nn);
        nx_x = wrap ? px_[0] : px_[t + 1];
        nx_y = wrap ? py_[0] : py_[t + 1];
      }
      s += px_[t] * nx_y - nx_x * py_[t];
    }
  }
  float area = 0.5f * fabsf(s);
  return (n >= 3) ? area : 0.f;
}

// ---------------------------------------------------------------------------
// MEGA kernel: one block per (image,class) group. decode -> rank-sort ->
// AABB-filtered pairwise IoU -> greedy NMS -> emit candidate keys + records.
// ---------------------------------------------------------------------------
__global__ void __launch_bounds__(256, 1)
mega_kernel(const float* __restrict__ logits,
            const float* __restrict__ breg,
            const float* __restrict__ rrects,
            u64* __restrict__ cand,      // [G*DET] keys (desc per group)
            float* __restrict__ rec) {   // [G*DET][12] bb4,rr5,score,label
  int g = blockIdx.x;
  int b = g / CF, cf = g % CF, c = cf + 1;
  int tid = threadIdx.x;

  __shared__ u64   lkey[P_];
  __shared__ u64   skey[P_];
  __shared__ int   sidx[P_];
  __shared__ float lptx[P_][4];
  __shared__ float lpty[P_][4];
  __shared__ float laabb[P_][4];
  __shared__ float lpr5[P_][5];
  __shared__ float larea[P_];
  __shared__ u32   sup[P_ * 16];
  __shared__ u32   skeep[16];
  __shared__ u32   q[CHUNK];
  __shared__ int   sV, qn;

  if (tid == 0) sV = 0;
  __syncthreads();

  // ---- Phase A: decode 2 proposals/thread ----
  u64 kreg[2];
  #pragma unroll
  for (int e = 0; e < 2; ++e) {
    int p = tid + e * 256;
    int n = b * P_ + p;
    const float* lg = logits + n * C_;
    float mx = lg[0];
    for (int k = 1; k < C_; ++k) mx = fmaxf(mx, lg[k]);
    float den = 0.f;
    for (int k = 0; k < C_; ++k) den += expf(lg[k] - mx);
    float sc = expf(lg[c] - mx) / den;

    const float* d = breg + n * (C_ * 5) + c * 5;
    float dx = d[0] / 10.0f, dy = d[1] / 10.0f;
    float dw = d[2] / 5.0f, dh = d[3] / 5.0f, da = d[4] / 3.0f;
    dw = fminf(dw, BBOX_CLIP);
    dh = fminf(dh, BBOX_CLIP);
    const float* an = rrects + n * 5;
    float px = dx * an[3] + an[0];
    float py = dy * an[3] + an[1];
    // NOTE: reference uses w for x and h for y:
    px = dx * an[2] + an[0];
    py = dy * an[3] + an[1];
    float pw = expf(dw) * an[2];
    float ph = expf(dh) * an[3];
    float pa = da * 57.29577951308232f + an[4];

    lpr5[p][0] = px; lpr5[p][1] = py; lpr5[p][2] = pw; lpr5[p][3] = ph; lpr5[p][4] = pa;
    larea[p] = pw * ph;

    float t = pa * 0.017453292519943295f;
    float cs = cosf(t), sn = sinf(t);
    float hx = pw * 0.5f, hy = ph * 0.5f;
    float ox[4] = {-hx, hx, hx, -hx};
    float oy[4] = {-hy, -hy, hy, hy};
    float minx = 1e30f, miny = 1e30f, maxx = -1e30f, maxy = -1e30f;
    #pragma unroll
    for (int qq = 0; qq < 4; ++qq) {
      float x = px + cs * ox[qq] - sn * oy[qq];
      float y = py + sn * ox[qq] + cs * oy[qq];
      lptx[p][qq] = x; lpty[p][qq] = y;
      minx = fminf(minx, x); maxx = fmaxf(maxx, x);
      miny = fminf(miny, y); maxy = fmaxf(maxy, y);
    }
    laabb[p][0] = minx; laabb[p][1] = miny; laabb[p][2] = maxx; laabb[p][3] = maxy;

    bool valid = sc > SCORE_THRESH;
    float v = valid ? sc : -1.0f;
    if (valid) atomicAdd(&sV, 1);
    u64 key = ((u64)f2o(v) << 32) | (u32)(~(u32)p);
    lkey[p] = key;
    kreg[e] = key;
  }
  __syncthreads();

  // ---- Phase B: rank-scatter sort (keys distinct) + zero sup ----
  {
    u64 k0 = kreg[0], k1 = kreg[1];
    int r0 = 0, r1 = 0;
    for (int s = 0; s < P_; ++s) {
      u64 ks = lkey[s];
      r0 += (ks > k0) ? 1 : 0;
      r1 += (ks > k1) ? 1 : 0;
    }
    skey[r0] = k0; sidx[r0] = tid;
    skey[r1] = k1; sidx[r1] = tid + 256;
    for (int w = tid; w < P_ * 16; w += 256) sup[w] = 0u;
  }
  __syncthreads();

  // ---- Phase C: chunked pairwise suppression over valid prefix ----
  int V = sV;
  int Tp = V * (V - 1) / 2;
  for (int base = 0; base < Tp; base += CHUNK) {
    int cnt = Tp - base; if (cnt > CHUNK) cnt = CHUNK;
    if (tid == 0) qn = 0;
    __syncthreads();
    for (int t = tid; t < cnt; t += 256) {
      int kk = base + t;
      float kf = (float)kk;
      int i = (int)((1.0f + sqrtf(1.0f + 8.0f * kf)) * 0.5f);
      while (i * (i - 1) / 2 > kk) --i;
      while ((i + 1) * i / 2 <= kk) ++i;
      int j = kk - i * (i - 1) / 2;
      int oi = sidx[i], oj = sidx[j];
      bool ov = (laabb[oi][0] <= laabb[oj][2]) && (laabb[oj][0] <= laabb[oi][2]) &&
                (laabb[oi][1] <= laabb[oj][3]) && (laabb[oj][1] <= laabb[oi][3]);
      if (ov) {
        int s = atomicAdd(&qn, 1);
        q[s] = (u32)((i << 9) | j);
      }
    }
    __syncthreads();
    int nq = qn;
    for (int s = tid; s < nq; s += 256) {
      u32 pk = q[s];
      int i = (int)(pk >> 9), j = (int)(pk & 511);
      int oi = sidx[i], oj = sidx[j];
      float qx[4] = {lptx[oi][0], lptx[oi][1], lptx[oi][2], lptx[oi][3]};
      float qy[4] = {lpty[oi][0], lpty[oi][1], lpty[oi][2], lpty[oi][3]};
      float rx[4] = {lptx[oj][0], lptx[oj][1], lptx[oj][2], lptx[oj][3]};
      float ry[4] = {lpty[oj][0], lpty[oj][1], lpty[oj][2], lpty[oj][3]};
      // reference iou[i][j]: clip quad i by edges of quad j
      float inter = inter_area_reg(qx, qy, rx, ry);
      float iou = inter / (((larea[oi] + larea[oj]) - inter) + 1e-8f);
      if (iou > NMS_THR)
        atomicOr(&sup[i * 16 + (j >> 5)], 1u << (j & 31));
    }
    __syncthreads();
  }

  // ---- Phase D: wave-0 sequential greedy over bitmask rows ----
  if (tid < 64) {
    u32 keepw = 0;
    u32 cur = (tid < 16 && V > 0) ? sup[tid] : 0u;
    for (int i = 0; i < V; ++i) {
      u32 nxt = (tid < 16 && (i + 1) < V) ? sup[(i + 1) * 16 + tid] : 0u;
      bool supd = __any((cur & keepw) != 0u);
      if (!supd && tid == (i >> 5)) keepw |= 1u << (i & 31);
      cur = nxt;
    }
    if (tid < 16) skeep[tid] = keepw;
  }
  __syncthreads();

  // ---- Phase E: emit candidate keys + records ----
  int tot = 0;
  #pragma unroll
  for (int t = 0; t < 16; ++t) tot += __popc(skeep[t]);
  for (int r = tid; r < V; r += 256) {
    if ((skeep[r >> 5] >> (r & 31)) & 1u) {
      int slot = __popc(skeep[r >> 5] & ((1u << (r & 31)) - 1u));
      for (int t = 0; t < (r >> 5); ++t) slot += __popc(skeep[t]);
      if (slot < DET) {
        u64 key = skey[r];
        int oi = sidx[r];
        int flat = cf * P_ + r;
        cand[g * DET + slot] = ((key >> 32) << 32) | (u32)(~(u32)flat);
        float* rr = rec + (size_t)(g * DET + slot) * 12;
        rr[0] = fminf(fmaxf(laabb[oi][0], 0.f), 1023.0f);
        rr[1] = fminf(fmaxf(laabb[oi][1], 0.f), 799.0f);
        rr[2] = fminf(fmaxf(laabb[oi][2], 0.f), 1023.0f);
        rr[3] = fminf(fmaxf(laabb[oi][3], 0.f), 799.0f);
        rr[4] = lpr5[oi][0]; rr[5] = lpr5[oi][1]; rr[6] = lpr5[oi][2];
        rr[7] = lpr5[oi][3]; rr[8] = lpr5[oi][4];
        rr[9] = o2f((u32)(key >> 32));
        rr[10] = (float)(cf + 1);
        rr[11] = 0.f;
      }
    }
  }
  int fill = tot < DET ? tot : DET;
  for (int s = fill + tid; s < DET; s += 256) cand[g * DET + s] = 0ull;
}

// ---------------------------------------------------------------------------
// K2: per-image top-100 by rank (per-group binary search over the 20 sorted
// candidate lists; 140 probes vs 2000 linear). Scatter record to row `rank`.
// out layout: bb[2,100,4] | rr[2,100,5] | sc[2,100] | lab[2,100] (all f32);
// zeros pre-filled by hipMemsetAsync.
// ---------------------------------------------------------------------------
__global__ void rank_kernel(const u64* __restrict__ cand, const float* __restrict__ rec,
                            float* __restrict__ out) {
  int b = blockIdx.y;
  int tid = threadIdx.x;
  __shared__ u64 lc[NC];
  for (int i = tid; i < NC; i += 256) lc[i] = cand[b * NC + i];
  __syncthreads();
  int ci = blockIdx.x * 256 + tid;
  if (ci >= NC) return;
  u64 k = lc[ci];
  if (k == 0ull) return;
  int rank = 0;
  #pragma unroll
  for (int gp = 0; gp < CF; ++gp) {
    int lo = 0, hi = DET;
    while (lo < hi) {            // first idx with lc[gp*DET+idx] <= k (desc list)
      int mid = (lo + hi) >> 1;
      if (lc[gp * DET + mid] > k) lo = mid + 1; else hi = mid;
    }
    rank += lo;
  }
  if (rank >= DET) return;
  const float* rr = rec + (size_t)(b * NC + ci) * 12;
  int o_bb = (b * DET + rank) * 4;
  int o_rr = B_ * DET * 4 + (b * DET + rank) * 5;
  int o_sc = B_ * DET * 9 + b * DET + rank;
  int o_lab = B_ * DET * 10 + b * DET + rank;
  out[o_bb + 0] = rr[0]; out[o_bb + 1] = rr[1];
  out[o_bb + 2] = rr[2]; out[o_bb + 3] = rr[3];
  out[o_rr + 0] = rr[4]; out[o_rr + 1] = rr[5]; out[o_rr + 2] = rr[6];
  out[o_rr + 3] = rr[7]; out[o_rr + 4] = rr[8];
  out[o_sc] = rr[9];
  out[o_lab] = rr[10];
}

// ---------------------------------------------------------------------------
extern "C" void kernel_launch(void* const* d_in, const int* in_sizes, int n_in,
                              void* d_out, int out_size, void* d_ws, size_t ws_size,
                              hipStream_t stream) {
  const float* logits = (const float*)d_in[0];
  const float* breg   = (const float*)d_in[1];
  const float* rrects = (const float*)d_in[2];
  float* out = (float*)d_out;

  const int G = B_ * CF;
  u64*   cand = (u64*)d_ws;                    // G*DET u64
  float* rec  = (float*)(cand + G * DET);      // G*DET*12 f32

  hipMemsetAsync(d_out, 0, (size_t)out_size * sizeof(float), stream);
  mega_kernel<<<G, 256, 0, stream>>>(logits, breg, rrects, cand, rec);
  rank_kernel<<<dim3((NC + 255) / 256, B_), 256, 0, stream>>>(cand, rec, out);
}

// Round 6
// 133.401 us; speedup vs baseline: 1.4515x; 1.4515x over previous
//
#include <hip/hip_runtime.h>
#include <stdint.h>

#pragma clang fp contract(off)

#define B_ 2
#define P_ 512
#define C_ 21
#define CF 20            // foreground classes
#define DET 100
#define SCORE_THRESH 0.05f
#define NMS_THR 0.5f
#define BBOX_CLIP 4.135166556742356f   // log(1000/16)
#define NC (CF * DET)    // 2000 candidates per image

typedef unsigned long long u64;
typedef unsigned int u32;

__device__ __forceinline__ u32 f2o(float f) {
  u32 u = __float_as_uint(f);
  return (u & 0x80000000u) ? ~u : (u | 0x80000000u);
}
__device__ __forceinline__ float o2f(u32 o) {
  u32 u = (o & 0x80000000u) ? (o ^ 0x80000000u) : ~o;
  return __uint_as_float(u);
}

// ---------------------------------------------------------------------------
// K1 (prep): per-(image,class) decode + rank-scatter sort (1 barrier).
// Scatters sorted-order pts / unclipped aabb / pr5 / area / score for the
// valid prefix only; zeroes this group's suppression slice; writes V.
// ---------------------------------------------------------------------------
__global__ void __launch_bounds__(256)
prep_kernel(const float* __restrict__ logits,
            const float* __restrict__ breg,
            const float* __restrict__ rrects,
            float* __restrict__ scsS,   // [G*P] sorted scores (valid prefix)
            float* __restrict__ ptsS,   // [G*P][8] sorted pts
            float* __restrict__ aabbS,  // [G*P][4] sorted unclipped aabb
            float* __restrict__ pr5S,   // [G*P][5] sorted proposals
            float* __restrict__ areaS,  // [G*P] sorted area
            int* __restrict__ gV,
            u64* __restrict__ sup) {
  int g = blockIdx.x;
  int b = g / CF, cf = g % CF, c = cf + 1;
  int tid = threadIdx.x;

  __shared__ u64 lkey[P_];
  __shared__ int cnt;
  if (tid == 0) cnt = 0;

  // ---- decode 2 proposals/thread, keep data in registers ----
  u64 kreg[2];
  float fx[2][4], fy[2][4];      // corner pts
  float fab[2][4];               // unclipped aabb
  float fp5[2][5];               // decoded rrect
  float far_[2];                 // area
  float fsc[2];                  // masked score
  #pragma unroll
  for (int e = 0; e < 2; ++e) {
    int p = tid + e * 256;
    int n = b * P_ + p;
    const float* lg = logits + n * C_;
    float mx = lg[0];
    for (int k = 1; k < C_; ++k) mx = fmaxf(mx, lg[k]);
    float den = 0.f;
    for (int k = 0; k < C_; ++k) den += expf(lg[k] - mx);
    float sc = expf(lg[c] - mx) / den;

    const float* d = breg + n * (C_ * 5) + c * 5;
    float dx = d[0] / 10.0f, dy = d[1] / 10.0f;
    float dw = d[2] / 5.0f, dh = d[3] / 5.0f, da = d[4] / 3.0f;
    dw = fminf(dw, BBOX_CLIP);
    dh = fminf(dh, BBOX_CLIP);
    const float* an = rrects + n * 5;
    float px = dx * an[2] + an[0];
    float py = dy * an[3] + an[1];
    float pw = expf(dw) * an[2];
    float ph = expf(dh) * an[3];
    float pa = da * 57.29577951308232f + an[4];
    fp5[e][0] = px; fp5[e][1] = py; fp5[e][2] = pw; fp5[e][3] = ph; fp5[e][4] = pa;
    far_[e] = pw * ph;

    float t = pa * 0.017453292519943295f;
    float cs = cosf(t), sn = sinf(t);
    float hx = pw * 0.5f, hy = ph * 0.5f;
    float ox[4] = {-hx, hx, hx, -hx};
    float oy[4] = {-hy, -hy, hy, hy};
    float minx = 1e30f, miny = 1e30f, maxx = -1e30f, maxy = -1e30f;
    #pragma unroll
    for (int qq = 0; qq < 4; ++qq) {
      float x = px + cs * ox[qq] - sn * oy[qq];
      float y = py + sn * ox[qq] + cs * oy[qq];
      fx[e][qq] = x; fy[e][qq] = y;
      minx = fminf(minx, x); maxx = fmaxf(maxx, x);
      miny = fminf(miny, y); maxy = fmaxf(maxy, y);
    }
    fab[e][0] = minx; fab[e][1] = miny; fab[e][2] = maxx; fab[e][3] = maxy;

    bool valid = sc > SCORE_THRESH;
    float v = valid ? sc : -1.0f;
    fsc[e] = v;
    u64 key = ((u64)f2o(v) << 32) | (u32)(~(u32)p);
    lkey[p] = key;
    kreg[e] = key;
    // wave ballot count of valid
    u64 m = __ballot(valid);
    if ((tid & 63) == 0) atomicAdd(&cnt, __popcll(m));
  }
  // zero this group's suppression slice while waiting
  for (int w = tid; w < P_ * 8; w += 256) sup[(size_t)g * P_ * 8 + w] = 0ull;
  __syncthreads();

  // ---- rank of each key (keys distinct) ----
  u64 k0 = kreg[0], k1 = kreg[1];
  int r0 = 0, r1 = 0;
  for (int s = 0; s < P_; ++s) {
    u64 ks = lkey[s];                // broadcast read
    r0 += (ks > k0) ? 1 : 0;
    r1 += (ks > k1) ? 1 : 0;
  }
  // ---- scatter valid entries to sorted slots ----
  #pragma unroll
  for (int e = 0; e < 2; ++e) {
    if (fsc[e] > 0.f) {
      int r = (e == 0) ? r0 : r1;
      int so = g * P_ + r;
      scsS[so] = fsc[e];
      ((float4*)ptsS)[so * 2]     = make_float4(fx[e][0], fx[e][1], fx[e][2], fx[e][3]);
      ((float4*)ptsS)[so * 2 + 1] = make_float4(fy[e][0], fy[e][1], fy[e][2], fy[e][3]);
      ((float4*)aabbS)[so] = make_float4(fab[e][0], fab[e][1], fab[e][2], fab[e][3]);
      pr5S[so * 5 + 0] = fp5[e][0]; pr5S[so * 5 + 1] = fp5[e][1];
      pr5S[so * 5 + 2] = fp5[e][2]; pr5S[so * 5 + 3] = fp5[e][3];
      pr5S[so * 5 + 4] = fp5[e][4];
      areaS[so] = far_[e];
    }
  }
  if (tid == 0) gV[g] = cnt;
}

// ---------------------------------------------------------------------------
// exact convex quad-quad intersection area — register-resident, bit-identical
// float op order vs reference (fp contract off). Clips quad q by edges of r.
// ---------------------------------------------------------------------------
__device__ __forceinline__ float inter_area_reg(const float qx[4], const float qy[4],
                                                const float rx[4], const float ry[4]) {
  float px_[8], py_[8];
  #pragma unroll
  for (int t = 0; t < 8; ++t) { px_[t] = (t < 4) ? qx[t] : 0.f; py_[t] = (t < 4) ? qy[t] : 0.f; }
  int n = 4;
  #pragma unroll
  for (int e = 0; e < 4; ++e) {
    float a0 = rx[e], a1 = ry[e];
    float b0 = rx[(e + 1) & 3], b1 = ry[(e + 1) & 3];
    float dx = b0 - a0, dy = b1 - a1;
    float ox_[8], oy_[8];
    #pragma unroll
    for (int t = 0; t < 8; ++t) { ox_[t] = 0.f; oy_[t] = 0.f; }
    float cr[8];
    #pragma unroll
    for (int t = 0; t < 8; ++t) cr[t] = dx * (py_[t] - a1) - dy * (px_[t] - a0);
    int m = 0;
    int nn = (n > 1) ? n : 1;
    #pragma unroll
    for (int t = 0; t < 8; ++t) {
      bool act = t < n;
      float sx = px_[t], sy = py_[t];
      float ex, ey, ce;
      if (t == 7) { ex = px_[0]; ey = py_[0]; ce = cr[0]; }
      else {
        bool wrap = (t + 1 == nn);
        ex = wrap ? px_[0] : px_[t + 1];
        ey = wrap ? py_[0] : py_[t + 1];
        ce = wrap ? cr[0] : cr[t + 1];
      }
      float cs = cr[t];
      float denom = cs - ce;
      float dn = (fabsf(denom) > 1e-12f) ? denom : 1e-12f;
      float tt = cs / dn;
      float ipx = sx + tt * (ex - sx);
      float ipy = sy + tt * (ey - sy);
      bool s_in = cs >= 0.f, e_in = ce >= 0.f;
      bool app1 = act && (s_in != e_in);
      #pragma unroll
      for (int s2 = 0; s2 < 8; ++s2) {
        bool wr = app1 && (m == s2);
        ox_[s2] = wr ? ipx : ox_[s2];
        oy_[s2] = wr ? ipy : oy_[s2];
      }
      m += app1 ? 1 : 0;
      bool app2 = act && e_in;
      #pragma unroll
      for (int s2 = 0; s2 < 8; ++s2) {
        bool wr = app2 && (m == s2);
        ox_[s2] = wr ? ex : ox_[s2];
        oy_[s2] = wr ? ey : oy_[s2];
      }
      m += app2 ? 1 : 0;
    }
    n = m;
    #pragma unroll
    for (int t = 0; t < 8; ++t) { px_[t] = ox_[t]; py_[t] = oy_[t]; }
  }
  int nn = (n > 1) ? n : 1;
  float s = 0.f;
  #pragma unroll
  for (int t = 0; t < 8; ++t) {
    if (t < n) {
      float nx_x, nx_y;
      if (t == 7) { nx_x = px_[0]; nx_y = py_[0]; }
      else {
        bool wrap = (t + 1 == nn);
        nx_x = wrap ? px_[0] : px_[t + 1];
        nx_y = wrap ? py_[0] : py_[t + 1];
      }
      s += px_[t] * nx_y - nx_x * py_[t];
    }
  }
  float area = 0.5f * fabsf(s);
  return (n >= 3) ? area : 0.f;
}

// ---------------------------------------------------------------------------
// K2 (pair): AABB-filter + LDS-compact + dense IoU over surviving pairs.
// grid = (128, 40); 256 thr x 4 pair-slots = 1024 pairs/block.
// ---------------------------------------------------------------------------
#define PPT 4
#define TPB 256
__global__ void pair_kernel(const int* __restrict__ gV,
                            const float* __restrict__ aabbS,
                            const float* __restrict__ areaS,
                            const float* __restrict__ ptsS,
                            u64* __restrict__ sup) {
  int g = blockIdx.y;
  int V = gV[g];
  int Tp = V * (V - 1) / 2;
  int base = blockIdx.x * (TPB * PPT);
  if (base >= Tp) return;
  __shared__ u32 q[TPB * PPT];
  __shared__ int qn;
  int tid = threadIdx.x;
  if (tid == 0) qn = 0;
  __syncthreads();
  const float4* ab = (const float4*)aabbS;
  for (int t = 0; t < PPT; ++t) {
    int kk = base + t * TPB + tid;
    if (kk >= Tp) break;
    float kf = (float)kk;
    int i = (int)((1.0f + sqrtf(1.0f + 8.0f * kf)) * 0.5f);
    while (i * (i - 1) / 2 > kk) --i;
    while ((i + 1) * i / 2 <= kk) ++i;
    int j = kk - i * (i - 1) / 2;
    float4 bi = ab[g * P_ + i];
    float4 bj = ab[g * P_ + j];
    bool ov = (bi.x <= bj.z) && (bj.x <= bi.z) && (bi.y <= bj.w) && (bj.y <= bi.w);
    if (ov) {
      int s = atomicAdd(&qn, 1);
      q[s] = (u32)((i << 9) | j);
    }
  }
  __syncthreads();
  int nq = qn;
  const float4* pS = (const float4*)ptsS;
  for (int s = tid; s < nq; s += TPB) {
    u32 pk = q[s];
    int i = (int)(pk >> 9), j = (int)(pk & 511);
    float4 ax = pS[(g * P_ + i) * 2];
    float4 ay = pS[(g * P_ + i) * 2 + 1];
    float4 bx = pS[(g * P_ + j) * 2];
    float4 by = pS[(g * P_ + j) * 2 + 1];
    float qx[4] = {ax.x, ax.y, ax.z, ax.w};
    float qy[4] = {ay.x, ay.y, ay.z, ay.w};
    float rx[4] = {bx.x, bx.y, bx.z, bx.w};
    float ry[4] = {by.x, by.y, by.z, by.w};
    float ai = areaS[g * P_ + i];
    float aj = areaS[g * P_ + j];
    // reference iou[i][j]: clip quad i by edges of quad j
    float inter = inter_area_reg(qx, qy, rx, ry);
    float iou = inter / (((ai + aj) - inter) + 1e-8f);
    if (iou > NMS_THR)
      atomicOr(&sup[((size_t)g * P_ + i) * 8 + (j >> 6)], 1ull << (j & 63));
  }
}

// ---------------------------------------------------------------------------
// K3 (greedy): sequential greedy over bitmask rows (prefetched) + emit keys
// and 12-float records for the first 100 kept per group.
// ---------------------------------------------------------------------------
__global__ void greedy_kernel(const float* __restrict__ scsS, const int* __restrict__ gV,
                              const float* __restrict__ aabbS, const float* __restrict__ pr5S,
                              const u64* __restrict__ sup,
                              u64* __restrict__ cand, float* __restrict__ rec) {
  int g = blockIdx.x;
  int tid = threadIdx.x;   // 64
  __shared__ u64 lsup[P_ * 8];
  __shared__ u32 skeep[16];
  int V = gV[g];
  for (int w = tid; w < V * 8; w += 64) lsup[w] = sup[(size_t)g * P_ * 8 + w];
  __syncthreads();
  u64 keepw = 0;
  u64 cur = (tid < 8 && V > 0) ? lsup[tid] : 0ull;
  for (int i = 0; i < V; ++i) {
    u64 nxt = (tid < 8 && (i + 1) < V) ? lsup[(i + 1) * 8 + tid] : 0ull;  // prefetch
    bool supd = __any((cur & keepw) != 0ull);
    if (!supd && tid == (i >> 6)) keepw |= 1ull << (i & 63);
    cur = nxt;
  }
  if (tid < 8) { skeep[tid * 2] = (u32)keepw; skeep[tid * 2 + 1] = (u32)(keepw >> 32); }
  __syncthreads();
  int cls = g % CF;
  int tot = 0;
  #pragma unroll
  for (int t = 0; t < 16; ++t) tot += __popc(skeep[t]);
  for (int r = tid; r < V; r += 64) {
    if ((skeep[r >> 5] >> (r & 31)) & 1u) {
      int slot = __popc(skeep[r >> 5] & ((1u << (r & 31)) - 1u));
      for (int t = 0; t < (r >> 5); ++t) slot += __popc(skeep[t]);
      if (slot < DET) {
        float sv = scsS[g * P_ + r];
        int flat = cls * P_ + r;
        cand[g * DET + slot] = ((u64)f2o(sv) << 32) | (u32)(~(u32)flat);
        int so = g * P_ + r;
        float* rr = rec + (size_t)(g * DET + slot) * 12;
        rr[0] = fminf(fmaxf(aabbS[so * 4 + 0], 0.f), 1023.0f);
        rr[1] = fminf(fmaxf(aabbS[so * 4 + 1], 0.f), 799.0f);
        rr[2] = fminf(fmaxf(aabbS[so * 4 + 2], 0.f), 1023.0f);
        rr[3] = fminf(fmaxf(aabbS[so * 4 + 3], 0.f), 799.0f);
        rr[4] = pr5S[so * 5 + 0]; rr[5] = pr5S[so * 5 + 1]; rr[6] = pr5S[so * 5 + 2];
        rr[7] = pr5S[so * 5 + 3]; rr[8] = pr5S[so * 5 + 4];
        rr[9] = sv;
        rr[10] = (float)(cls + 1);
        rr[11] = 0.f;
      }
    }
  }
  int fill = tot < DET ? tot : DET;
  for (int s = fill + tid; s < DET; s += 64) cand[g * DET + s] = 0ull;
}

// ---------------------------------------------------------------------------
// K4 (rank): per-image top-100 by rank (binary search per sorted group list);
// scatter record to row `rank`; zero-fill unused rows in-kernel (no memset).
// out layout: bb[2,100,4] | rr[2,100,5] | sc[2,100] | lab[2,100] (all f32)
// ---------------------------------------------------------------------------
__global__ void rank_kernel(const u64* __restrict__ cand, const float* __restrict__ rec,
                            float* __restrict__ out) {
  int b = blockIdx.y;
  int tid = threadIdx.x;
  __shared__ u64 lc[NC];
  __shared__ int ncand;
  if (tid == 0) ncand = 0;
  __syncthreads();
  int nz = 0;
  for (int i = tid; i < NC; i += 256) {
    u64 v = cand[b * NC + i];
    lc[i] = v;
    nz += (v != 0ull) ? 1 : 0;
  }
  u64 m = __ballot(nz > 0);   // cheap guard: only lanes with nz>0 atomicAdd
  if (nz > 0) atomicAdd(&ncand, nz);
  (void)m;
  __syncthreads();
  int ci = blockIdx.x * 256 + tid;
  if (ci >= NC) return;
  // zero-fill unused rows from block 0
  if (blockIdx.x == 0 && tid < DET && tid >= ncand) {
    int o_bb = (b * DET + tid) * 4;
    int o_rr = B_ * DET * 4 + (b * DET + tid) * 5;
    int o_sc = B_ * DET * 9 + b * DET + tid;
    int o_lab = B_ * DET * 10 + b * DET + tid;
    out[o_bb + 0] = 0.f; out[o_bb + 1] = 0.f; out[o_bb + 2] = 0.f; out[o_bb + 3] = 0.f;
    out[o_rr + 0] = 0.f; out[o_rr + 1] = 0.f; out[o_rr + 2] = 0.f;
    out[o_rr + 3] = 0.f; out[o_rr + 4] = 0.f;
    out[o_sc] = 0.f;
    out[o_lab] = 0.f;
  }
  u64 k = lc[ci];
  if (k == 0ull) return;
  int rank = 0;
  #pragma unroll
  for (int gp = 0; gp < CF; ++gp) {
    int lo = 0, hi = DET;
    while (lo < hi) {            // first idx with lc[gp*DET+idx] <= k (desc list)
      int mid = (lo + hi) >> 1;
      if (lc[gp * DET + mid] > k) lo = mid + 1; else hi = mid;
    }
    rank += lo;
  }
  if (rank >= DET) return;
  const float* rr = rec + (size_t)(b * NC + ci) * 12;
  int o_bb = (b * DET + rank) * 4;
  int o_rr = B_ * DET * 4 + (b * DET + rank) * 5;
  int o_sc = B_ * DET * 9 + b * DET + rank;
  int o_lab = B_ * DET * 10 + b * DET + rank;
  out[o_bb + 0] = rr[0]; out[o_bb + 1] = rr[1];
  out[o_bb + 2] = rr[2]; out[o_bb + 3] = rr[3];
  out[o_rr + 0] = rr[4]; out[o_rr + 1] = rr[5]; out[o_rr + 2] = rr[6];
  out[o_rr + 3] = rr[7]; out[o_rr + 4] = rr[8];
  out[o_sc] = rr[9];
  out[o_lab] = rr[10];
}

// ---------------------------------------------------------------------------
extern "C" void kernel_launch(void* const* d_in, const int* in_sizes, int n_in,
                              void* d_out, int out_size, void* d_ws, size_t ws_size,
                              hipStream_t stream) {
  const float* logits = (const float*)d_in[0];
  const float* breg   = (const float*)d_in[1];
  const float* rrects = (const float*)d_in[2];
  float* out = (float*)d_out;

  const int G = B_ * CF;
  u64*   sup  = (u64*)d_ws;                          // G*P*8 u64 = 1.31 MB
  u64*   cand = sup + (size_t)G * P_ * 8;            // G*DET u64
  int*   gV   = (int*)(cand + G * DET);              // 64 ints (padded)
  float* scsS = (float*)(gV + 64);                   // G*P
  float* ptsS = scsS + (size_t)G * P_;               // G*P*8
  float* aabbS = ptsS + (size_t)G * P_ * 8;          // G*P*4
  float* pr5S = aabbS + (size_t)G * P_ * 4;          // G*P*5
  float* areaS = pr5S + (size_t)G * P_ * 5;          // G*P
  float* rec  = areaS + (size_t)G * P_;              // G*DET*12

  prep_kernel<<<G, 256, 0, stream>>>(logits, breg, rrects,
                                     scsS, ptsS, aabbS, pr5S, areaS, gV, sup);
  pair_kernel<<<dim3(128, G), TPB, 0, stream>>>(gV, aabbS, areaS, ptsS, sup);
  greedy_kernel<<<G, 64, 0, stream>>>(scsS, gV, aabbS, pr5S, sup, cand, rec);
  rank_kernel<<<dim3((NC + 255) / 256, B_), 256, 0, stream>>>(cand, rec, out);
}